// Round 4
// baseline (945.372 us; speedup 1.0000x reference)
//
#include <hip/hip_runtime.h>
#include <hip/hip_bf16.h>
#include <stdint.h>

#define NN 50000
#define NE 800000
#define DD 256
#define NL 4
#define NRL 4
#define KT 1280  // NRL*DD + DD (logical K of the fused GEMM)
#define KA 1024  // NRL*DD (columns stored in Abig; root block comes from Xbf)
#define NMT 782  // ceil(NN/64) m-tiles
#define MTB 131072  // bytes per A m-tile: 32 k-tiles * 64 rows * 64 B
#define NTILE 40    // K tiles of 32 elems (64 B)

typedef float f32x4 __attribute__((ext_vector_type(4)));
typedef __bf16 bf16x8 __attribute__((ext_vector_type(8)));
typedef __bf16 bf16x4 __attribute__((ext_vector_type(4)));
typedef unsigned short u16x4 __attribute__((ext_vector_type(4)));

static __device__ __forceinline__ unsigned short f2bf(float f) {
  __bf16 h = (__bf16)f;
  return __builtin_bit_cast(unsigned short, h);
}

static __device__ __forceinline__ u16x4 pk4(f32x4 v) {
  u16x4 o;
  o.x = f2bf(v.x); o.y = f2bf(v.y); o.z = f2bf(v.z); o.w = f2bf(v.w);
  return o;
}

// ---------------- edge preprocessing (once per call) ----------------

__global__ __launch_bounds__(256) void k_hist(const int* __restrict__ ei,
                                              const int* __restrict__ et,
                                              int* __restrict__ cntNR) {
  int e = blockIdx.x * 256 + threadIdx.x;
  if (e >= NE) return;
  int dst = ei[NE + e];
  int r = et[e];
  atomicAdd(&cntNR[dst * 4 + r], 1);
}

__global__ __launch_bounds__(256) void k_scan1(const int* __restrict__ cntNR,
                                               int* __restrict__ offs,
                                               int* __restrict__ bsum) {
  __shared__ int sd[256];
  const int t = threadIdx.x;
  const int n = blockIdx.x * 256 + t;
  int deg = 0;
  if (n < NN) {
    const int* c = cntNR + n * 4;
    deg = c[0] + c[1] + c[2] + c[3];
  }
  sd[t] = deg;
  __syncthreads();
  int val = deg;
  for (int d = 1; d < 256; d <<= 1) {
    int other = (t >= d) ? sd[t - d] : 0;
    __syncthreads();
    val += other;
    sd[t] = val;
    __syncthreads();
  }
  if (n < NN) offs[n] = val - deg;  // exclusive
  if (t == 255) bsum[blockIdx.x] = val;
}

__global__ __launch_bounds__(256) void k_scan2(const int* __restrict__ bsum,
                                               int* __restrict__ boff, int nb) {
  __shared__ int sd[256];
  const int t = threadIdx.x;
  int v = (t < nb) ? bsum[t] : 0;
  sd[t] = v;
  __syncthreads();
  int val = v;
  for (int d = 1; d < 256; d <<= 1) {
    int other = (t >= d) ? sd[t - d] : 0;
    __syncthreads();
    val += other;
    sd[t] = val;
    __syncthreads();
  }
  boff[t] = val - v;  // exclusive
}

__global__ __launch_bounds__(256) void k_scan3(int* __restrict__ offs,
                                               const int* __restrict__ boff,
                                               int* __restrict__ cursor) {
  int n = blockIdx.x * 256 + threadIdx.x;
  if (n < NN) {
    int o = offs[n] + boff[blockIdx.x];
    offs[n] = o;
    cursor[n] = o;
  }
  if (n == 0) offs[NN] = NE;
}

__global__ __launch_bounds__(256) void k_scatter(const int* __restrict__ ei,
                                                 const int* __restrict__ et,
                                                 int* __restrict__ cursor,
                                                 uint32_t* __restrict__ packed) {
  int e = blockIdx.x * 256 + threadIdx.x;
  if (e >= NE) return;
  int src = ei[e];
  int dst = ei[NE + e];
  int r = et[e];
  int pos = atomicAdd(&cursor[dst], 1);
  packed[pos] = (uint32_t)src | ((uint32_t)r << 16);  // src < 65536 ok
}

// Build tiled B (LINEAR, no swizzle — fragments are loaded direct to VGPR now):
// WbigT[l][kt=0..39][row=0..255][slot=0..3][e=0..7] bf16,
// content at (kt,row,slot,e) = B^T[row][k], k = kt*32 + slot*8 + e,
// where B^T[o][k] = (k<1024) ? weights[l][k>>8][k&255][o] : roots[l][k-1024][o].
// An MFMA B-fragment (16 rows x 16B at stride 64B) is a coalesced 1KB wave-load.
__global__ __launch_bounds__(256) void k_wconv(const float* __restrict__ weights,
                                               const float* __restrict__ roots,
                                               __hip_bfloat16* __restrict__ WbigT) {
  int idx = blockIdx.x * 256 + threadIdx.x;
  if (idx >= NL * DD * KT) return;  // 1,310,720 = 4*40*256*32
  int l = idx / 327680;             // 40*256*32
  int rem = idx - l * 327680;
  int kt = rem / 8192;              // 256*32
  int rem2 = rem - kt * 8192;
  int row = rem2 >> 5;
  int q = rem2 & 31;
  int k = kt * 32 + q;
  float v;
  if (k < KA) {
    int r = k >> 8, i = k & 255;
    v = weights[(((size_t)(l * NRL + r) * DD) + i) * DD + row];
  } else {
    int i = k - KA;
    v = roots[((size_t)l * DD + i) * DD + row];
  }
  WbigT[idx] = __float2bfloat16(v);
}

// one-time fp32 -> bf16 cast of the input embedding (4 elems/thread)
__global__ __launch_bounds__(256) void k_cast(const float* __restrict__ X,
                                              __hip_bfloat16* __restrict__ Xbf) {
  int i = blockIdx.x * 256 + threadIdx.x;
  if (i >= NN * 64) return;
  const f32x4* Xv = (const f32x4*)X;
  ((u16x4*)Xbf)[i] = pk4(Xv[i]);
}

// ---------------- per-layer aggregation: one wave per node, pipelined bf16 gather ------
// Output layout is the GEMM fragment-tiled form (LINEAR, no swizzle):
// Abig[mtile][kt=0..31][row=0..63][64B], content = A[node=mtile*64+row][k-bytes kt*64..+64].

__global__ __launch_bounds__(256) void k_agg(const __hip_bfloat16* __restrict__ Xbf,
                                             const uint32_t* __restrict__ packed,
                                             const int* __restrict__ offs,
                                             const int* __restrict__ cntNR,
                                             __hip_bfloat16* __restrict__ Abig) {
  const int wid = (blockIdx.x * 256 + threadIdx.x) >> 6;
  const int lane = threadIdx.x & 63;
  if (wid >= NN) return;
  const int beg = offs[wid];
  const int end = offs[wid + 1];
  const bf16x4* __restrict__ Xv = (const bf16x4*)Xbf;

  f32x4 a0 = {0.f, 0.f, 0.f, 0.f}, a1 = a0, a2 = a0, a3 = a0;

  // depth-8 software pipeline: 8 packed loads, then 8 row-gathers in flight,
  // then accumulate (r is wave-uniform -> scalar branch)
  for (int e = beg; e < end; e += 8) {
    uint32_t pv[8];
    bf16x4 vv[8];
#pragma unroll
    for (int i = 0; i < 8; ++i) {
      int ee = e + i;
      ee = (ee < end) ? ee : (end - 1);
      pv[i] = packed[ee];
    }
#pragma unroll
    for (int i = 0; i < 8; ++i) {
      vv[i] = Xv[(int)(pv[i] & 0xFFFFu) * 64 + lane];
    }
    const int nv = end - e;
#pragma unroll
    for (int i = 0; i < 8; ++i) {
      if (i < nv) {
        int r = (int)(pv[i] >> 16);
        f32x4 v = {(float)vv[i][0], (float)vv[i][1], (float)vv[i][2], (float)vv[i][3]};
        if (r == 0) a0 += v;
        else if (r == 1) a1 += v;
        else if (r == 2) a2 += v;
        else a3 += v;
      }
    }
  }

  const int* c = cntNR + wid * 4;
  int c0 = c[0], c1 = c[1], c2 = c[2], c3 = c[3];
  float s0 = 1.0f / (float)(c0 > 1 ? c0 : 1);
  float s1 = 1.0f / (float)(c1 > 1 ? c1 : 1);
  float s2 = 1.0f / (float)(c2 > 1 ? c2 : 1);
  float s3 = 1.0f / (float)(c3 > 1 ? c3 : 1);

  // Tiled LINEAR scatter store.  Lane holds dims [lane*4, lane*4+4) (8 B) of each
  // relation r.  k-byte = r*512 + lane*8 -> kt = r*8 + (lane>>3), byte-in-row = (lane&7)*8.
  {
    const int row = wid & 63;
    char* Ab = (char*)Abig + (size_t)(wid >> 6) * MTB + (size_t)(lane >> 3) * 4096 +
               row * 64 + (lane & 7) * 8;
    *(u16x4*)(Ab + 0 * 32768) = pk4(a0 * s0);  // r: kt += 8 -> +32768 B
    *(u16x4*)(Ab + 1 * 32768) = pk4(a1 * s1);
    *(u16x4*)(Ab + 2 * 32768) = pk4(a2 * s2);
    *(u16x4*)(Ab + 3 * 32768) = pk4(a3 * s3);
  }
}

// ---------------- GEMM + bias + LayerNorm + ELU + residual (+ bf16 X for next layer) ----
// C[m, n] = [Abig | Xbf][m, 0:1280] @ WbigT[n, 0:1280]^T ; BM=64, BN=256, BK=32.
// NO LDS in the main loop: both operands are pre-tiled in MFMA fragment order, so
// every fragment is a coalesced 1KB wave-load straight into VGPRs.  (Round-3 PMC
// arithmetic showed the LDS staging pipe carried ~6x the MFMA pipe's work: 8 waves
// x 15KB/iter through 128 B/cy = ~940 cy/iter vs 78 cy of MFMA -> the staging
// machinery WAS the kernel.  Eliminated wholesale.)
// 4 waves: wave w covers all 64 rows x cols [w*64, w*64+64): acc[4][4] f32x4.
// 2-deep register prefetch, #pragma unroll 2 for static buffer indexing.
// No barriers in the loop; latency hidden by 3 blocks/CU (grid 782 ~= 1 full pass).

__global__ __launch_bounds__(256, 3) void k_gemm(const __hip_bfloat16* __restrict__ A,
                                                 const __hip_bfloat16* __restrict__ Xbf_in,
                                                 const __hip_bfloat16* __restrict__ Bt,
                                                 const float* __restrict__ bias,
                                                 const float* __restrict__ gamma,
                                                 const float* __restrict__ beta,
                                                 const float* __restrict__ Xin,
                                                 float* __restrict__ Xout,
                                                 __hip_bfloat16* __restrict__ Xbf_out) {
  __shared__ float sRed[64][8];

  const int tid = threadIdx.x;
  const int w = tid >> 6;
  const int lane = tid & 63;
  const int quad = lane >> 4, l15 = lane & 15;
  const int mBase = blockIdx.x * 64;

  // per-lane fragment base pointers (fragment = 16 rows x 16B, row-stride 64B)
  const char* aT = (const char*)A + (size_t)blockIdx.x * MTB + l15 * 64 + quad * 16;
  const char* bT = (const char*)Bt + w * 4096 + l15 * 64 + quad * 16;
  // root tiles (kt>=32) come from row-major Xbf: node-row stride 512B
  const char* xR = (const char*)Xbf_in + (size_t)(mBase + l15) * 512 + quad * 16;

  f32x4 acc[4][4];
#pragma unroll
  for (int i = 0; i < 4; ++i)
#pragma unroll
    for (int j = 0; j < 4; ++j) acc[i][j] = (f32x4){0.f, 0.f, 0.f, 0.f};

  bf16x8 a[2][4], b[2][4];

  auto LOADT = [&](int s, int tt) {
#pragma unroll
    for (int mt = 0; mt < 4; ++mt) {
      const char* pa = (tt < 32) ? (aT + (size_t)tt * 4096 + mt * 1024)
                                 : (xR + mt * 8192 + (tt - 32) * 64);
      a[s][mt] = *(const bf16x8*)pa;
    }
#pragma unroll
    for (int nt = 0; nt < 4; ++nt) {
      b[s][nt] = *(const bf16x8*)(bT + (size_t)tt * 16384 + nt * 1024);
    }
  };

  LOADT(0, 0);
#pragma unroll 2
  for (int t = 0; t < NTILE; ++t) {
    const int s = t & 1;
    const int tn = (t + 1 < NTILE) ? (t + 1) : (NTILE - 1);
    LOADT(s ^ 1, tn);  // next tile's 8 fragment loads stay in flight behind the MFMAs
#pragma unroll
    for (int mt = 0; mt < 4; ++mt)
#pragma unroll
      for (int nt = 0; nt < 4; ++nt)
        acc[mt][nt] =
            __builtin_amdgcn_mfma_f32_16x16x32_bf16(a[s][mt], b[s][nt], acc[mt][nt], 0, 0, 0);
  }

  // ---- epilogue: bias, LN (full 256-wide rows in-block), ELU, residual ----
  float bv[4], gv[4], bev[4];
#pragma unroll
  for (int nt = 0; nt < 4; ++nt) {
    int n = w * 64 + nt * 16 + l15;
    bv[nt] = bias[n];
    gv[nt] = gamma[n];
    bev[nt] = beta[n];
  }

#pragma unroll
  for (int mt = 0; mt < 4; ++mt) {
#pragma unroll
    for (int reg = 0; reg < 4; ++reg) {
      float s = 0.f, q = 0.f;
#pragma unroll
      for (int nt = 0; nt < 4; ++nt) {
        float v = acc[mt][nt][reg] + bv[nt];
        acc[mt][nt][reg] = v;
        s += v;
        q += v * v;
      }
#pragma unroll
      for (int d = 1; d < 16; d <<= 1) {
        s += __shfl_xor(s, d, 64);
        q += __shfl_xor(q, d, 64);
      }
      if (l15 == 0) {
        int row = mt * 16 + quad * 4 + reg;
        sRed[row][w * 2] = s;
        sRed[row][w * 2 + 1] = q;
      }
    }
  }
  __syncthreads();

#pragma unroll
  for (int mt = 0; mt < 4; ++mt) {
#pragma unroll
    for (int reg = 0; reg < 4; ++reg) {
      int row = mt * 16 + quad * 4 + reg;
      float ts = sRed[row][0] + sRed[row][2] + sRed[row][4] + sRed[row][6];
      float tq = sRed[row][1] + sRed[row][3] + sRed[row][5] + sRed[row][7];
      float mean = ts * (1.0f / 256.0f);
      float var = tq * (1.0f / 256.0f) - mean * mean;
      float rstd = rsqrtf(var + 1e-5f);
      int m = mBase + row;
      if (m < NN) {
#pragma unroll
        for (int nt = 0; nt < 4; ++nt) {
          int n = w * 64 + nt * 16 + l15;
          float v = (acc[mt][nt][reg] - mean) * rstd * gv[nt] + bev[nt];
          v = v > 0.0f ? v : (__expf(v) - 1.0f);
          // fp32 X streams are read/written exactly once per layer: NT so the
          // 2x51MB streams don't evict Abig/Xbf from L3
          float res = v + __builtin_nontemporal_load(&Xin[(size_t)m * 256 + n]);
          __builtin_nontemporal_store(res, &Xout[(size_t)m * 256 + n]);
          Xbf_out[(size_t)m * 256 + n] = __float2bfloat16(res);
        }
      }
    }
  }
}

// ---------------- host side ----------------

extern "C" void kernel_launch(void* const* d_in, const int* in_sizes, int n_in,
                              void* d_out, int out_size, void* d_ws, size_t ws_size,
                              hipStream_t stream) {
  const float* X0 = (const float*)d_in[0];
  const float* weights = (const float*)d_in[1];
  const float* roots = (const float*)d_in[2];
  const float* biases = (const float*)d_in[3];
  const float* ln_g = (const float*)d_in[4];
  const float* ln_b = (const float*)d_in[5];
  const int* eidx = (const int*)d_in[6];
  const int* etyp = (const int*)d_in[7];
  float* out = (float*)d_out;

  char* ws = (char*)d_ws;
  size_t off = 0;
  auto alloc = [&](size_t bytes) -> char* {
    char* p = ws + off;
    off = (off + bytes + 255) & ~(size_t)255;
    return p;
  };
  __hip_bfloat16* Abig = (__hip_bfloat16*)alloc((size_t)NMT * MTB);             // 102.5 MB tiled
  __hip_bfloat16* WbigT = (__hip_bfloat16*)alloc((size_t)NL * DD * KT * 2);     // 2.6 MB tiled
  float* Xb0 = (float*)alloc((size_t)NN * DD * 4);                              // 51.2 MB
  float* Xb1 = (float*)alloc((size_t)NN * DD * 4);                              // 51.2 MB
  __hip_bfloat16* Xbf0 = (__hip_bfloat16*)alloc((size_t)NN * DD * 2);           // 25.6 MB
  __hip_bfloat16* Xbf1 = (__hip_bfloat16*)alloc((size_t)NN * DD * 2);           // 25.6 MB
  int* cntNR = (int*)alloc((size_t)NN * 4 * 4);
  int* offs = (int*)alloc((size_t)(NN + 1) * 4);
  int* cursor = (int*)alloc((size_t)NN * 4);
  uint32_t* packed = (uint32_t*)alloc((size_t)NE * 4);
  int* bsum = (int*)alloc(256 * 4);
  int* boff = (int*)alloc(256 * 4);
  (void)ws_size; (void)in_sizes; (void)n_in; (void)out_size;

  (void)hipMemsetAsync(cntNR, 0, (size_t)NN * 16, stream);
  // zero the tail m-tile of Abig once per call: rows 16..63 of m-tile 781 are never
  // written by k_agg (nodes >= NN) but are read by the last k_gemm block.
  (void)hipMemsetAsync((char*)Abig + (size_t)(NMT - 1) * MTB, 0, MTB, stream);
  k_hist<<<(NE + 255) / 256, 256, 0, stream>>>(eidx, etyp, cntNR);
  const int NB = (NN + 255) / 256;  // 196
  k_scan1<<<NB, 256, 0, stream>>>(cntNR, offs, bsum);
  k_scan2<<<1, 256, 0, stream>>>(bsum, boff, NB);
  k_scan3<<<NB, 256, 0, stream>>>(offs, boff, cursor);
  k_scatter<<<(NE + 255) / 256, 256, 0, stream>>>(eidx, etyp, cursor, packed);
  k_wconv<<<(NL * DD * KT + 255) / 256, 256, 0, stream>>>(weights, roots, WbigT);
  k_cast<<<(NN * 64 + 255) / 256, 256, 0, stream>>>(X0, Xbf0);

  const float* Xin = X0;
  for (int l = 0; l < NL; ++l) {
    float* Xout = (l == NL - 1) ? out : ((l & 1) ? Xb1 : Xb0);
    const __hip_bfloat16* Xbin = (l & 1) ? Xbf1 : Xbf0;
    __hip_bfloat16* Xbout = (l & 1) ? Xbf0 : Xbf1;
    k_agg<<<(NN * 64 + 255) / 256, 256, 0, stream>>>(Xbin, packed, offs, cntNR, Abig);
    k_gemm<<<NMT, 256, 0, stream>>>(Abig, Xbin,
                                    WbigT + (size_t)l * DD * KT,
                                    biases + (size_t)l * DD,
                                    ln_g + (size_t)l * DD,
                                    ln_b + (size_t)l * DD, Xin, Xout, Xbout);
    Xin = Xout;
  }
}

// Round 5
// 815.658 us; speedup vs baseline: 1.1590x; 1.1590x over previous
//
#include <hip/hip_runtime.h>
#include <hip/hip_bf16.h>
#include <stdint.h>

#define NN 50000
#define NE 800000
#define DD 256
#define NL 4
#define NRL 4
#define KT 1280  // NRL*DD + DD (logical K of the fused GEMM)
#define KA 1024  // NRL*DD (columns stored in Abig; root block comes from Xbf)
#define NMT 782  // ceil(NN/64) m-tiles
#define MTB 131072  // bytes per A m-tile: 32 k-tiles * 64 rows * 64 B
#define NTILE 40    // K tiles of 32 elems (64 B)

typedef float f32x4 __attribute__((ext_vector_type(4)));
typedef __bf16 bf16x8 __attribute__((ext_vector_type(8)));
typedef __bf16 bf16x4 __attribute__((ext_vector_type(4)));
typedef unsigned short u16x4 __attribute__((ext_vector_type(4)));

static __device__ __forceinline__ unsigned short f2bf(float f) {
  __bf16 h = (__bf16)f;
  return __builtin_bit_cast(unsigned short, h);
}

static __device__ __forceinline__ u16x4 pk4(f32x4 v) {
  u16x4 o;
  o.x = f2bf(v.x); o.y = f2bf(v.y); o.z = f2bf(v.z); o.w = f2bf(v.w);
  return o;
}

static __device__ __forceinline__ void async16(const void* g, void* l) {
  __builtin_amdgcn_global_load_lds(
      (const __attribute__((address_space(1))) unsigned int*)g,
      (__attribute__((address_space(3))) unsigned int*)l, 16, 0, 0);
}

// ---------------- edge preprocessing (once per call) ----------------

__global__ __launch_bounds__(256) void k_hist(const int* __restrict__ ei,
                                              const int* __restrict__ et,
                                              int* __restrict__ cntNR) {
  int e = blockIdx.x * 256 + threadIdx.x;
  if (e >= NE) return;
  int dst = ei[NE + e];
  int r = et[e];
  atomicAdd(&cntNR[dst * 4 + r], 1);
}

__global__ __launch_bounds__(256) void k_scan1(const int* __restrict__ cntNR,
                                               int* __restrict__ offs,
                                               int* __restrict__ bsum) {
  __shared__ int sd[256];
  const int t = threadIdx.x;
  const int n = blockIdx.x * 256 + t;
  int deg = 0;
  if (n < NN) {
    const int* c = cntNR + n * 4;
    deg = c[0] + c[1] + c[2] + c[3];
  }
  sd[t] = deg;
  __syncthreads();
  int val = deg;
  for (int d = 1; d < 256; d <<= 1) {
    int other = (t >= d) ? sd[t - d] : 0;
    __syncthreads();
    val += other;
    sd[t] = val;
    __syncthreads();
  }
  if (n < NN) offs[n] = val - deg;  // exclusive
  if (t == 255) bsum[blockIdx.x] = val;
}

__global__ __launch_bounds__(256) void k_scan2(const int* __restrict__ bsum,
                                               int* __restrict__ boff, int nb) {
  __shared__ int sd[256];
  const int t = threadIdx.x;
  int v = (t < nb) ? bsum[t] : 0;
  sd[t] = v;
  __syncthreads();
  int val = v;
  for (int d = 1; d < 256; d <<= 1) {
    int other = (t >= d) ? sd[t - d] : 0;
    __syncthreads();
    val += other;
    sd[t] = val;
    __syncthreads();
  }
  boff[t] = val - v;  // exclusive
}

__global__ __launch_bounds__(256) void k_scan3(int* __restrict__ offs,
                                               const int* __restrict__ boff,
                                               int* __restrict__ cursor) {
  int n = blockIdx.x * 256 + threadIdx.x;
  if (n < NN) {
    int o = offs[n] + boff[blockIdx.x];
    offs[n] = o;
    cursor[n] = o;
  }
  if (n == 0) offs[NN] = NE;
}

__global__ __launch_bounds__(256) void k_scatter(const int* __restrict__ ei,
                                                 const int* __restrict__ et,
                                                 int* __restrict__ cursor,
                                                 uint32_t* __restrict__ packed) {
  int e = blockIdx.x * 256 + threadIdx.x;
  if (e >= NE) return;
  int src = ei[e];
  int dst = ei[NE + e];
  int r = et[e];
  int pos = atomicAdd(&cursor[dst], 1);
  packed[pos] = (uint32_t)src | ((uint32_t)r << 16);  // src < 65536 ok
}

// Build tiled+pre-swizzled B: WbigT[l][kt=0..39][row=0..255][slot=0..3][e=0..7] bf16,
// content at (kt,row,slot,e) = B^T[row][k] with k = kt*32 + (slot^((row>>1)&3))*8 + e,
// where B^T[o][k] = (k<1024) ? weights[l][k>>8][k&255][o] : roots[l][k-1024][o].
// Every k_gemm B staging load is a CONTIGUOUS 1KB burst; the slot swizzle keeps
// ds_read_b128 at free 2-way bank aliasing.
__global__ __launch_bounds__(256) void k_wconv(const float* __restrict__ weights,
                                               const float* __restrict__ roots,
                                               __hip_bfloat16* __restrict__ WbigT) {
  int idx = blockIdx.x * 256 + threadIdx.x;
  if (idx >= NL * DD * KT) return;  // 1,310,720 = 4*40*256*32
  int l = idx / 327680;             // 40*256*32
  int rem = idx - l * 327680;
  int kt = rem / 8192;              // 256*32
  int rem2 = rem - kt * 8192;
  int row = rem2 >> 5;
  int q = rem2 & 31;
  int s = q >> 3, e = q & 7;
  int k = kt * 32 + ((s ^ ((row >> 1) & 3)) << 3) + e;
  float v;
  if (k < KA) {
    int r = k >> 8, i = k & 255;
    v = weights[(((size_t)(l * NRL + r) * DD) + i) * DD + row];
  } else {
    int i = k - KA;
    v = roots[((size_t)l * DD + i) * DD + row];
  }
  WbigT[idx] = __float2bfloat16(v);
}

// one-time fp32 -> bf16 cast of the input embedding (4 elems/thread)
__global__ __launch_bounds__(256) void k_cast(const float* __restrict__ X,
                                              __hip_bfloat16* __restrict__ Xbf) {
  int i = blockIdx.x * 256 + threadIdx.x;
  if (i >= NN * 64) return;
  const f32x4* Xv = (const f32x4*)X;
  ((u16x4*)Xbf)[i] = pk4(Xv[i]);
}

// ---------------- per-layer aggregation: one wave per node, pipelined bf16 gather ------
// Output layout is the GEMM-staging-tiled form: Abig[mtile][kt=0..31][row=0..63][slot][8B]
// content at (kt,row,slot) = A[node=mtile*64+row][k-bytes kt*64 + (slot^((row>>1)&3))*16].

__global__ __launch_bounds__(256) void k_agg(const __hip_bfloat16* __restrict__ Xbf,
                                             const uint32_t* __restrict__ packed,
                                             const int* __restrict__ offs,
                                             const int* __restrict__ cntNR,
                                             __hip_bfloat16* __restrict__ Abig) {
  const int wid = (blockIdx.x * 256 + threadIdx.x) >> 6;
  const int lane = threadIdx.x & 63;
  if (wid >= NN) return;
  const int beg = offs[wid];
  const int end = offs[wid + 1];
  const bf16x4* __restrict__ Xv = (const bf16x4*)Xbf;

  f32x4 a0 = {0.f, 0.f, 0.f, 0.f}, a1 = a0, a2 = a0, a3 = a0;

  // depth-8 software pipeline: 8 packed loads, then 8 row-gathers in flight,
  // then accumulate (r is wave-uniform -> scalar branch)
  for (int e = beg; e < end; e += 8) {
    uint32_t pv[8];
    bf16x4 vv[8];
#pragma unroll
    for (int i = 0; i < 8; ++i) {
      int ee = e + i;
      ee = (ee < end) ? ee : (end - 1);
      pv[i] = packed[ee];
    }
#pragma unroll
    for (int i = 0; i < 8; ++i) {
      vv[i] = Xv[(int)(pv[i] & 0xFFFFu) * 64 + lane];
    }
    const int nv = end - e;
#pragma unroll
    for (int i = 0; i < 8; ++i) {
      if (i < nv) {
        int r = (int)(pv[i] >> 16);
        f32x4 v = {(float)vv[i][0], (float)vv[i][1], (float)vv[i][2], (float)vv[i][3]};
        if (r == 0) a0 += v;
        else if (r == 1) a1 += v;
        else if (r == 2) a2 += v;
        else a3 += v;
      }
    }
  }

  const int* c = cntNR + wid * 4;
  int c0 = c[0], c1 = c[1], c2 = c[2], c3 = c[3];
  float s0 = 1.0f / (float)(c0 > 1 ? c0 : 1);
  float s1 = 1.0f / (float)(c1 > 1 ? c1 : 1);
  float s2 = 1.0f / (float)(c2 > 1 ? c2 : 1);
  float s3 = 1.0f / (float)(c3 > 1 ? c3 : 1);

  // Tiled+swizzled scatter store. Lane holds dims [lane*4, lane*4+4) (8 B) of each
  // relation.  k-byte = r*512 + lane*8 -> kt = r*8 + (lane>>3); 16B-slot within the
  // 64B chunk = (lane>>1)&3, swizzled by f=(row>>1)&3; byte-in-slot = (lane&1)*8.
  {
    const int row = wid & 63;
    const int fsw = (row >> 1) & 3;
    char* Ab = (char*)Abig + (size_t)(wid >> 6) * MTB + (size_t)(lane >> 3) * 4096 +
               row * 64 + ((((lane >> 1) & 3) ^ fsw) << 4) + (lane & 1) * 8;
    *(u16x4*)(Ab + 0 * 32768) = pk4(a0 * s0);  // r: kt += 8 -> +32768 B
    *(u16x4*)(Ab + 1 * 32768) = pk4(a1 * s1);
    *(u16x4*)(Ab + 2 * 32768) = pk4(a2 * s2);
    *(u16x4*)(Ab + 3 * 32768) = pk4(a3 * s3);
  }
}

// ---------------- GEMM + bias + LayerNorm + ELU + residual (+ bf16 X for next layer) ----
// C[m, n] = [Abig | Xbf][m, 0:1280] @ WbigT[n, 0:1280]^T ; BM=128, BN=256, BK=32.
// 8 waves (512 thr) in 4m x 2n: each wave 32 rows x 128 cols = 2x8 MFMA tiles
// (same per-wave shape as the proven round-3 kernel; block is 2x bigger to
// amortize the measured ~per-iteration overhead over 2x the output rows).
// 3-buffer LDS pipeline, depth-2 prefetch, counted vmcnt:
//   iter t: wait vmcnt(3) [retires tile t] -> barrier -> STAGE(t+2) -> COMPUTE(t).
//   Stage-AFTER-barrier makes 3 buffers race-free at depth 2: when any wave
//   issues STAGE(t+2) it has passed barrier(t), so every wave finished
//   COMPUTE(t-1) -> overwriting buf (t+2)%3 == (t-1)%3 is safe.
//   Per wave per tile: 1 A + 2 B global_load_lds = 3 vmem ops; steady in-flight 6.
//   Tail peels vmcnt 3 -> 0.

#define GBUF 24576  // per-buffer LDS bytes: A 128x64B (8KB) + B 256x64B (16KB)

__global__ __launch_bounds__(512, 4) void k_gemm(const __hip_bfloat16* __restrict__ A,
                                                 const __hip_bfloat16* __restrict__ Xbf_in,
                                                 const __hip_bfloat16* __restrict__ Bt,
                                                 const float* __restrict__ bias,
                                                 const float* __restrict__ gamma,
                                                 const float* __restrict__ beta,
                                                 const float* __restrict__ Xin,
                                                 float* __restrict__ Xout,
                                                 __hip_bfloat16* __restrict__ Xbf_out) {
  __shared__ __align__(16) char sLDS[3 * GBUF];  // 72KB
  __shared__ float sRed[128][4];                 // 2KB

  const int tid = threadIdx.x;
  const int w = tid >> 6;  // 0..7
  const int lane = tid & 63;
  const int wm = w >> 1, wn = w & 1;
  const int quad = lane >> 4, l15 = lane & 15;
  const int mBase = blockIdx.x * 128;

  // root-tile (scattered) staging lane map: applies the slot swizzle on the fly
  const int srow = lane >> 2;
  const int kc = (lane & 3) ^ ((srow >> 1) & 3);
  int am = mBase + w * 16 + srow;
  if (am >= NN) am = NN - 1;  // clamp (outputs are guarded; LN is per-row)
  const char* agx = (const char*)Xbf_in + (size_t)am * (DD * 2) + kc * 16;

  // tiled contiguous sources (content already swizzle-stored -> verbatim copy).
  // Wave w stages A rows [w*16, w*16+16): m-tile 2*b + (w>>2), local row (w&3)*16+srow.
  const char* agp = (const char*)A + (size_t)(2 * blockIdx.x + (w >> 2)) * MTB +
                    (w & 3) * 1024 + lane * 16;
  // Wave w stages B rows [w*32, w*32+32): two 1KB bursts.
  const char* bgp = (const char*)Bt + w * 2048 + lane * 16;

  // per-wave LDS staging bases (wave-uniform; lane deposits at base + lane*16)
  char* const lA = sLDS + w * 1024;
  char* const lB = sLDS + 8192 + w * 2048;

  f32x4 acc[2][8];
#pragma unroll
  for (int i = 0; i < 2; ++i)
#pragma unroll
    for (int j = 0; j < 8; ++j) acc[i][j] = (f32x4){0.f, 0.f, 0.f, 0.f};

  const int aslot = (quad ^ ((l15 >> 1) & 3)) * 16;
  const char* const aBase = sLDS + (wm * 32 + l15) * 64 + aslot;          // + buf*GBUF + mt*1024
  const char* const bBase = sLDS + 8192 + (wn * 128 + l15) * 64 + aslot;  // + buf*GBUF + nt*1024

  auto STAGE = [&](int buf, int ts) {
    char* la = lA + buf * GBUF;
    char* lb = lB + buf * GBUF;
    if (ts < 32) {
      async16(agp + (size_t)ts * 4096, la);  // contiguous 1KB
    } else {
      async16(agx + (ts - 32) * 64, la);     // root tiles: scattered rows of Xbf
    }
    const char* bt = bgp + (size_t)ts * 16384;  // contiguous 2x1KB
    async16(bt, lb);
    async16(bt + 1024, lb + 1024);
  };

  auto COMPUTE = [&](int buf) {
    const char* aAddr = aBase + buf * GBUF;
    const char* bAddr = bBase + buf * GBUF;
    bf16x8 a0 = *(const bf16x8*)(aAddr + 0 * 1024);
    bf16x8 a1 = *(const bf16x8*)(aAddr + 1 * 1024);
#pragma unroll
    for (int nt = 0; nt < 8; ++nt) {
      bf16x8 b = *(const bf16x8*)(bAddr + nt * 1024);
      acc[0][nt] = __builtin_amdgcn_mfma_f32_16x16x32_bf16(a0, b, acc[0][nt], 0, 0, 0);
      acc[1][nt] = __builtin_amdgcn_mfma_f32_16x16x32_bf16(a1, b, acc[1][nt], 0, 0, 0);
    }
  };

  STAGE(0, 0);  // prologue: tiles 0,1 in flight (6 vmem ops/wave)
  STAGE(1, 1);
  int cb = 0, sb = 2;
  for (int t = 0; t < NTILE - 2; ++t) {
    // retire tile t's 3 loads; tile t+1 (3 ops) stays in flight
    asm volatile("s_waitcnt vmcnt(3)" ::: "memory");
    __builtin_amdgcn_s_barrier();
    __builtin_amdgcn_sched_barrier(0);
    STAGE(sb, t + 2);  // safe: all waves are past barrier(t) -> done with buf (t-1)%3
    __builtin_amdgcn_sched_barrier(0);
    COMPUTE(cb);
    cb = (cb == 2) ? 0 : cb + 1;
    sb = (sb == 2) ? 0 : sb + 1;
  }
  // peeled tail: tiles 38,39 in flight; counts 3 -> 0
  asm volatile("s_waitcnt vmcnt(3)" ::: "memory");
  __builtin_amdgcn_s_barrier();
  __builtin_amdgcn_sched_barrier(0);
  COMPUTE(cb);
  cb = (cb == 2) ? 0 : cb + 1;
  asm volatile("s_waitcnt vmcnt(0)" ::: "memory");
  __builtin_amdgcn_s_barrier();
  __builtin_amdgcn_sched_barrier(0);
  COMPUTE(cb);

  // ---- epilogue: bias, LN (full 256-wide rows in-block), ELU, residual ----
  float bv[8], gv[8], bev[8];
#pragma unroll
  for (int nt = 0; nt < 8; ++nt) {
    int n = wn * 128 + nt * 16 + l15;
    bv[nt] = bias[n];
    gv[nt] = gamma[n];
    bev[nt] = beta[n];
  }

#pragma unroll
  for (int mt = 0; mt < 2; ++mt) {
#pragma unroll
    for (int reg = 0; reg < 4; ++reg) {
      float s = 0.f, q = 0.f;
#pragma unroll
      for (int nt = 0; nt < 8; ++nt) {
        float v = acc[mt][nt][reg] + bv[nt];
        acc[mt][nt][reg] = v;
        s += v;
        q += v * v;
      }
#pragma unroll
      for (int d = 1; d < 16; d <<= 1) {
        s += __shfl_xor(s, d, 64);
        q += __shfl_xor(q, d, 64);
      }
      if (l15 == 0) {
        int row = wm * 32 + mt * 16 + quad * 4 + reg;
        sRed[row][wn * 2] = s;
        sRed[row][wn * 2 + 1] = q;
      }
    }
  }
  __syncthreads();

#pragma unroll
  for (int mt = 0; mt < 2; ++mt) {
#pragma unroll
    for (int reg = 0; reg < 4; ++reg) {
      int row = wm * 32 + mt * 16 + quad * 4 + reg;
      float ts = sRed[row][0] + sRed[row][2];
      float tq = sRed[row][1] + sRed[row][3];
      float mean = ts * (1.0f / 256.0f);
      float var = tq * (1.0f / 256.0f) - mean * mean;
      float rstd = rsqrtf(var + 1e-5f);
      int m = mBase + row;
      if (m < NN) {
#pragma unroll
        for (int nt = 0; nt < 8; ++nt) {
          int n = wn * 128 + nt * 16 + l15;
          float v = (acc[mt][nt][reg] - mean) * rstd * gv[nt] + bev[nt];
          v = v > 0.0f ? v : (__expf(v) - 1.0f);
          // fp32 X streams are read/written exactly once per layer: NT so the
          // 2x51MB streams don't evict Abig/Xbf from L3
          float res = v + __builtin_nontemporal_load(&Xin[(size_t)m * 256 + n]);
          __builtin_nontemporal_store(res, &Xout[(size_t)m * 256 + n]);
          Xbf_out[(size_t)m * 256 + n] = __float2bfloat16(res);
        }
      }
    }
  }
}

// ---------------- host side ----------------

extern "C" void kernel_launch(void* const* d_in, const int* in_sizes, int n_in,
                              void* d_out, int out_size, void* d_ws, size_t ws_size,
                              hipStream_t stream) {
  const float* X0 = (const float*)d_in[0];
  const float* weights = (const float*)d_in[1];
  const float* roots = (const float*)d_in[2];
  const float* biases = (const float*)d_in[3];
  const float* ln_g = (const float*)d_in[4];
  const float* ln_b = (const float*)d_in[5];
  const int* eidx = (const int*)d_in[6];
  const int* etyp = (const int*)d_in[7];
  float* out = (float*)d_out;

  char* ws = (char*)d_ws;
  size_t off = 0;
  auto alloc = [&](size_t bytes) -> char* {
    char* p = ws + off;
    off = (off + bytes + 255) & ~(size_t)255;
    return p;
  };
  __hip_bfloat16* Abig = (__hip_bfloat16*)alloc((size_t)NMT * MTB);             // 102.5 MB tiled
  __hip_bfloat16* WbigT = (__hip_bfloat16*)alloc((size_t)NL * DD * KT * 2);     // 2.6 MB tiled
  float* Xb0 = (float*)alloc((size_t)NN * DD * 4);                              // 51.2 MB
  float* Xb1 = (float*)alloc((size_t)NN * DD * 4);                              // 51.2 MB
  __hip_bfloat16* Xbf0 = (__hip_bfloat16*)alloc((size_t)NN * DD * 2);           // 25.6 MB
  __hip_bfloat16* Xbf1 = (__hip_bfloat16*)alloc((size_t)NN * DD * 2);           // 25.6 MB
  int* cntNR = (int*)alloc((size_t)NN * 4 * 4);
  int* offs = (int*)alloc((size_t)(NN + 1) * 4);
  int* cursor = (int*)alloc((size_t)NN * 4);
  uint32_t* packed = (uint32_t*)alloc((size_t)NE * 4);
  int* bsum = (int*)alloc(256 * 4);
  int* boff = (int*)alloc(256 * 4);
  (void)ws_size; (void)in_sizes; (void)n_in; (void)out_size;

  (void)hipMemsetAsync(cntNR, 0, (size_t)NN * 16, stream);
  // zero the tail m-tile of Abig once per call: rows 16..63 of m-tile 781 are never
  // written by k_agg (nodes >= NN) but are read by the last k_gemm block.
  (void)hipMemsetAsync((char*)Abig + (size_t)(NMT - 1) * MTB, 0, MTB, stream);
  k_hist<<<(NE + 255) / 256, 256, 0, stream>>>(eidx, etyp, cntNR);
  const int NB = (NN + 255) / 256;  // 196
  k_scan1<<<NB, 256, 0, stream>>>(cntNR, offs, bsum);
  k_scan2<<<1, 256, 0, stream>>>(bsum, boff, NB);
  k_scan3<<<NB, 256, 0, stream>>>(offs, boff, cursor);
  k_scatter<<<(NE + 255) / 256, 256, 0, stream>>>(eidx, etyp, cursor, packed);
  k_wconv<<<(NL * DD * KT + 255) / 256, 256, 0, stream>>>(weights, roots, WbigT);
  k_cast<<<(NN * 64 + 255) / 256, 256, 0, stream>>>(X0, Xbf0);

  const float* Xin = X0;
  for (int l = 0; l < NL; ++l) {
    float* Xout = (l == NL - 1) ? out : ((l & 1) ? Xb1 : Xb0);
    const __hip_bfloat16* Xbin = (l & 1) ? Xbf1 : Xbf0;
    __hip_bfloat16* Xbout = (l & 1) ? Xbf0 : Xbf1;
    k_agg<<<(NN * 64 + 255) / 256, 256, 0, stream>>>(Xbin, packed, offs, cntNR, Abig);
    k_gemm<<<(NN + 127) / 128, 512, 0, stream>>>(Abig, Xbin,
                                                 WbigT + (size_t)l * DD * KT,
                                                 biases + (size_t)l * DD,
                                                 ln_g + (size_t)l * DD,
                                                 ln_b + (size_t)l * DD, Xin, Xout, Xbout);
    Xin = Xout;
  }
}